// Round 4
// baseline (259.497 us; speedup 1.0000x reference)
//
#include <hip/hip_runtime.h>
#include <hip/hip_bf16.h>
#include <stdint.h>

// Shape fixed by reference: B=2, S=1024 -> M=2048; N=4096; K=4096
#define M_DIM 2048
#define N_DIM 4096
#define K_DIM 4096

#define BM 128
#define BN 128
#define BK 128            // int8 elements per K-tile

#define BTILE (BN * BK)   // 16 KiB per B buffer
#define NT (K_DIM / BK)   // 32 K-tiles

typedef __attribute__((ext_vector_type(4))) int   int4v;
typedef __attribute__((ext_vector_type(4))) float f32x4;

__device__ __forceinline__ void load_lds16(const void* g, void* l) {
    __builtin_amdgcn_global_load_lds(
        (const __attribute__((address_space(1))) void*)g,
        (__attribute__((address_space(3))) void*)l,
        16, 0, 0);
}

// ---------- x: fp32 [M,K] -> int8 per-row dynamic quant; sx[row] = rowmax/127 ----------
__global__ __launch_bounds__(256) void quant_x(const float* __restrict__ x,
                                               int8_t* __restrict__ Aq,
                                               float* __restrict__ sx) {
    const int row = blockIdx.x;
    const int tid = threadIdx.x;
    const float4* xr = (const float4*)(x + (size_t)row * K_DIM);

    float4 v[4];
    float mx = 0.f;
#pragma unroll
    for (int p = 0; p < 4; p++) {
        v[p] = xr[p * 256 + tid];
        mx = fmaxf(mx, fmaxf(fmaxf(fabsf(v[p].x), fabsf(v[p].y)),
                             fmaxf(fabsf(v[p].z), fabsf(v[p].w))));
    }
#pragma unroll
    for (int off = 32; off >= 1; off >>= 1)
        mx = fmaxf(mx, __shfl_xor(mx, off, 64));

    __shared__ float wmax[4];
    __shared__ float smax;
    if ((tid & 63) == 0) wmax[tid >> 6] = mx;
    __syncthreads();
    if (tid == 0) {
        float m = fmaxf(fmaxf(wmax[0], wmax[1]), fmaxf(wmax[2], wmax[3]));
        m = fmaxf(m, 1e-20f);
        smax = m;
        sx[row] = m * (1.0f / 127.0f);
    }
    __syncthreads();
    const float inv = 127.0f / smax;

    int* out = (int*)Aq + (size_t)row * (K_DIM / 4);
#pragma unroll
    for (int p = 0; p < 4; p++) {
        int q0 = (int)__builtin_rintf(v[p].x * inv);
        int q1 = (int)__builtin_rintf(v[p].y * inv);
        int q2 = (int)__builtin_rintf(v[p].z * inv);
        int q3 = (int)__builtin_rintf(v[p].w * inv);
        q0 = max(-127, min(127, q0)); q1 = max(-127, min(127, q1));
        q2 = max(-127, min(127, q2)); q3 = max(-127, min(127, q3));
        out[p * 256 + tid] = (q0 & 255) | ((q1 & 255) << 8) |
                             ((q2 & 255) << 16) | ((q3 & 255) << 24);
    }
}

// ---------- w: int32 [N,K] (values in [-128,127]) -> int8, exact narrowing ----------
__global__ __launch_bounds__(256) void cvt_w8(const int* __restrict__ w,
                                              int8_t* __restrict__ Bq) {
    size_t i = ((size_t)blockIdx.x * 256 + threadIdx.x) * 16;
    int4 a0 = *(const int4*)(w + i);
    int4 a1 = *(const int4*)(w + i + 4);
    int4 a2 = *(const int4*)(w + i + 8);
    int4 a3 = *(const int4*)(w + i + 12);
    uint4 t;
    t.x = (a0.x & 255) | ((a0.y & 255) << 8) | ((a0.z & 255) << 16) | ((a0.w & 255) << 24);
    t.y = (a1.x & 255) | ((a1.y & 255) << 8) | ((a1.z & 255) << 16) | ((a1.w & 255) << 24);
    t.z = (a2.x & 255) | ((a2.y & 255) << 8) | ((a2.z & 255) << 16) | ((a2.w & 255) << 24);
    t.w = (a3.x & 255) | ((a3.y & 255) << 8) | ((a3.z & 255) << 16) | ((a3.w & 255) << 24);
    *(uint4*)(Bq + i) = t;
}

// ---------- GEMM: C = Aq[M,K] x Bq[N,K]^T (i8 MFMA, i32 acc), epilogue dequant ----------
// r8: r4's verified geometry (128x128 block, 8 waves 2x4 each 64x32, 2 blocks/CU,
// dbuf + drain-per-tile) with A moved OUT of LDS into registers.
// Post-mortem model: r4 was LDS-traffic-bound (reads+glds writes = 256 KiB/CU/iter
// = 85 B/cyc at 40.7us == measured ds_read_b128 ceiling). A-direct-to-reg cuts LDS
// to 96 KiB/CU/iter (B stage 16K write + B reads 64K read x2 blocks) -> LDS floor
// 15.4us < MFMA floor 17.4us. The 4 waves per wm-group read identical A bytes ->
// L1 dedups; A stays L2/L3-resident (8 MB, XCD swizzle groups same-bm blocks).
// A regs double-buffered (afA/afB, prefetch issued right after each barrier ->
// full tile of compute to land; the next barrier's vmcnt(0) drain covers them).
// B path byte-identical to r4 (verified): XOR-swizzled glds source, conflict-free
// ds_read_b128 (measured 0), identity k-chunks after swizzle cancellation. A is
// loaded in identity k-order directly (row = bm*128+wm+i*16+l16, bytes k0+h*64+
// quad*16), matching B's logical layout -> exact same arithmetic as r4.

__global__ __launch_bounds__(512, 4) void gemm_bt_i8(
    const int8_t* __restrict__ A,      // [M,K] int8
    const int8_t* __restrict__ B,      // [N,K] int8
    const float*  __restrict__ sx,     // [M] row dequant scale
    const float*  __restrict__ scales, // [N]
    const float*  __restrict__ bias,   // [N]
    float* __restrict__ C)             // [M,N]
{
    __shared__ __align__(16) int8_t Bs[2 * BTILE];  // 32 KiB only -> 2 blocks/CU

    const int tid  = threadIdx.x;

    // T1: XCD-aware swizzle. 512 blocks = 8 chunks of 64; chunk = 8(bm) x 8(bn)
    // tiles; chunks tile the 16x32 grid as 2x4.
    const int bid   = blockIdx.x;
    const int xcd   = bid & 7;
    const int local = bid >> 3;                       // 0..63
    const int bm    = (xcd >> 2) * 8 + (local >> 3);  // 0..15
    const int bn    = (xcd & 3) * 8 + (local & 7);    // 0..31

    const int lane = tid & 63;
    const int wave = tid >> 6;           // 0..7
    const int wm   = (wave >> 2) * 64;   // 0 or 64
    const int wn   = (wave & 3) * 32;    // 0,32,64,96
    const int l16  = lane & 15;
    const int quad = lane >> 4;
    const int swz  = l16 & 7;

    // B staging (r4 scheme): 512 thr x 16 B = 8 KiB/instr; 2 instrs per 16 KiB tile.
    // thread t -> row = t>>3 (+64 for seg1), phys colgroup = t&7; global colgroup
    // = phys ^ (row&7). LDS byte addr = 16*t (+8192): linear in tid (glds rule).
    const int srow = tid >> 3;           // 0..63
    const int cgl  = (tid & 7) ^ (srow & 7);

    const int8_t* gb0 = B + (size_t)(bn * BN + srow)      * K_DIM + cgl * 16;
    const int8_t* gb1 = B + (size_t)(bn * BN + 64 + srow) * K_DIM + cgl * 16;
    const int la = tid * 16;

    // A direct: lane (l16,quad) owns row bm*128+wm+i*16+l16, bytes k0+h*64+quad*16.
    const int8_t* Ap = A + (size_t)(bm * BM + wm + l16) * K_DIM + quad * 16;

    int4v afA[2][4], afB[2][4];
    int4v acc[4][2] = {};

#define PREA(dst, k0_) do {                                                  \
        _Pragma("unroll")                                                    \
        for (int h = 0; h < 2; h++)                                          \
            _Pragma("unroll")                                                \
            for (int i = 0; i < 4; i++)                                      \
                dst[h][i] = *(const int4v*)(Ap + (k0_) + i * (16 * K_DIM) + h * 64); \
    } while (0)

#define STAGEB(slot, k0_) do {                                               \
        load_lds16(gb0 + (k0_), Bs + (slot) * BTILE + la);                   \
        load_lds16(gb1 + (k0_), Bs + (slot) * BTILE + 8192 + la);            \
    } while (0)

#define COMP(af, slot) do {                                                  \
        const int8_t* Bb = Bs + (slot) * BTILE;                              \
        _Pragma("unroll")                                                    \
        for (int h = 0; h < 2; h++) {                                        \
            const int cp = (h * 4 + quad) ^ swz;                             \
            int4v bf0 = *(const int4v*)(Bb + (wn + l16) * BK + cp * 16);     \
            int4v bf1 = *(const int4v*)(Bb + (wn + 16 + l16) * BK + cp * 16);\
            _Pragma("unroll")                                                \
            for (int i = 0; i < 4; i++) {                                    \
                acc[i][0] = __builtin_amdgcn_mfma_i32_16x16x64_i8(           \
                    af[h][i], bf0, acc[i][0], 0, 0, 0);                      \
                acc[i][1] = __builtin_amdgcn_mfma_i32_16x16x64_i8(           \
                    af[h][i], bf1, acc[i][1], 0, 0, 0);                      \
            }                                                                \
        }                                                                    \
    } while (0)

    // Prologue: tile 0 A->regs + B->LDS buf0.
    PREA(afA, 0);
    STAGEB(0, 0);

    for (int t = 0; t < NT; t += 2) {
        __syncthreads();                 // drains: B(t) staged, A(t) regs loaded
        PREA(afB, (t + 1) * BK);         // prefetch tile t+1 (lands during COMP)
        STAGEB(1, (t + 1) * BK);
        COMP(afA, 0);

        __syncthreads();                 // drains: B(t+1) staged, afB loaded
        if (t + 2 < NT) {
            PREA(afA, (t + 2) * BK);
            STAGEB(0, (t + 2) * BK);
        }
        COMP(afB, 1);
    }

#undef PREA
#undef STAGEB
#undef COMP

    // Row dequant scales for this lane's 16 output rows.
    float sxr[16];
#pragma unroll
    for (int i = 0; i < 4; i++)
#pragma unroll
        for (int r = 0; r < 4; r++)
            sxr[i * 4 + r] = sx[bm * BM + wm + i * 16 + quad * 4 + r];

    // Epilogue. C/D layout (shape-determined, verified): col = lane&15, row = quad*4 + reg.
#pragma unroll
    for (int j = 0; j < 2; j++) {
        const int col = bn * BN + wn + j * 16 + l16;
        const float s = scales[col];
        const float b = bias[col];
#pragma unroll
        for (int i = 0; i < 4; i++) {
            const int row0 = bm * BM + wm + i * 16 + quad * 4;
#pragma unroll
            for (int r = 0; r < 4; r++) {
                C[(size_t)(row0 + r) * N_DIM + col] =
                    (float)acc[i][j][r] * (sxr[i * 4 + r] * s) + b;
            }
        }
    }
}

// ---------- launch ----------

extern "C" void kernel_launch(void* const* d_in, const int* in_sizes, int n_in,
                              void* d_out, int out_size, void* d_ws, size_t ws_size,
                              hipStream_t stream) {
    const float* x      = (const float*)d_in[0];   // [2,1024,4096] fp32
    const int*   w      = (const int*)d_in[1];     // [4096,4096] int, values in [-128,127]
    const float* scales = (const float*)d_in[2];   // [4096]
    const float* bias   = (const float*)d_in[3];   // [4096]
    float*       out    = (float*)d_out;           // [2,1024,4096] fp32

    int8_t* Aq = (int8_t*)d_ws;                                        // 8 MiB
    int8_t* Bq = (int8_t*)d_ws + (size_t)M_DIM * K_DIM;                // 16 MiB
    float*  sx = (float*)((int8_t*)d_ws + (size_t)(M_DIM + N_DIM) * K_DIM); // 8 KiB

    quant_x<<<M_DIM, 256, 0, stream>>>(x, Aq, sx);
    cvt_w8<<<(int)((size_t)N_DIM * K_DIM / 16 / 256), 256, 0, stream>>>(w, Bq);

    // 1-D grid of 512 blocks (16 bm x 32 bn), XCD-swizzled inside the kernel.
    gemm_bt_i8<<<512, 512, 0, stream>>>(Aq, Bq, sx, scales, bias, out);
}

// Round 5
// 164.991 us; speedup vs baseline: 1.5728x; 1.5728x over previous
//
#include <hip/hip_runtime.h>
#include <hip/hip_bf16.h>
#include <stdint.h>

// Shape fixed by reference: B=2, S=1024 -> M=2048; N=4096; K=4096
#define M_DIM 2048
#define N_DIM 4096
#define K_DIM 4096

#define BM 128
#define BN 128
#define BK 128            // int8 elements per K-tile = 128 B per row

#define ATILE (BM * BK)   // 16 KiB per A buffer
#define BTILE (BN * BK)
#define NT (K_DIM / BK)   // 32 K-tiles

typedef __attribute__((ext_vector_type(4))) int   int4v;
typedef __attribute__((ext_vector_type(4))) float f32x4;

__device__ __forceinline__ void load_lds16(const void* g, void* l) {
    __builtin_amdgcn_global_load_lds(
        (const __attribute__((address_space(1))) void*)g,
        (__attribute__((address_space(3))) void*)l,
        16, 0, 0);
}

// ---------- x: fp32 [M,K] -> int8 per-row dynamic quant; sx[row] = rowmax/127 ----------
__global__ __launch_bounds__(256) void quant_x(const float* __restrict__ x,
                                               int8_t* __restrict__ Aq,
                                               float* __restrict__ sx) {
    const int row = blockIdx.x;
    const int tid = threadIdx.x;
    const float4* xr = (const float4*)(x + (size_t)row * K_DIM);

    float4 v[4];
    float mx = 0.f;
#pragma unroll
    for (int p = 0; p < 4; p++) {
        v[p] = xr[p * 256 + tid];
        mx = fmaxf(mx, fmaxf(fmaxf(fabsf(v[p].x), fabsf(v[p].y)),
                             fmaxf(fabsf(v[p].z), fabsf(v[p].w))));
    }
#pragma unroll
    for (int off = 32; off >= 1; off >>= 1)
        mx = fmaxf(mx, __shfl_xor(mx, off, 64));

    __shared__ float wmax[4];
    __shared__ float smax;
    if ((tid & 63) == 0) wmax[tid >> 6] = mx;
    __syncthreads();
    if (tid == 0) {
        float m = fmaxf(fmaxf(wmax[0], wmax[1]), fmaxf(wmax[2], wmax[3]));
        m = fmaxf(m, 1e-20f);
        smax = m;
        sx[row] = m * (1.0f / 127.0f);
    }
    __syncthreads();
    const float inv = 127.0f / smax;

    int* out = (int*)Aq + (size_t)row * (K_DIM / 4);
#pragma unroll
    for (int p = 0; p < 4; p++) {
        int q0 = (int)__builtin_rintf(v[p].x * inv);
        int q1 = (int)__builtin_rintf(v[p].y * inv);
        int q2 = (int)__builtin_rintf(v[p].z * inv);
        int q3 = (int)__builtin_rintf(v[p].w * inv);
        q0 = max(-127, min(127, q0)); q1 = max(-127, min(127, q1));
        q2 = max(-127, min(127, q2)); q3 = max(-127, min(127, q3));
        out[p * 256 + tid] = (q0 & 255) | ((q1 & 255) << 8) |
                             ((q2 & 255) << 16) | ((q3 & 255) << 24);
    }
}

// ---------- w: int32 [N,K] (values in [-128,127]) -> int8, exact narrowing ----------
__global__ __launch_bounds__(256) void cvt_w8(const int* __restrict__ w,
                                              int8_t* __restrict__ Bq) {
    size_t i = ((size_t)blockIdx.x * 256 + threadIdx.x) * 16;
    int4 a0 = *(const int4*)(w + i);
    int4 a1 = *(const int4*)(w + i + 4);
    int4 a2 = *(const int4*)(w + i + 8);
    int4 a3 = *(const int4*)(w + i + 12);
    uint4 t;
    t.x = (a0.x & 255) | ((a0.y & 255) << 8) | ((a0.z & 255) << 16) | ((a0.w & 255) << 24);
    t.y = (a1.x & 255) | ((a1.y & 255) << 8) | ((a1.z & 255) << 16) | ((a1.w & 255) << 24);
    t.z = (a2.x & 255) | ((a2.y & 255) << 8) | ((a2.z & 255) << 16) | ((a2.w & 255) << 24);
    t.w = (a3.x & 255) | ((a3.y & 255) << 8) | ((a3.z & 255) << 16) | ((a3.w & 255) << 24);
    *(uint4*)(Bq + i) = t;
}

// ---------- GEMM: C = Aq[M,K] x Bq[N,K]^T (i8 MFMA, i32 acc), epilogue dequant ----------
// r9: r4's verified shell (128x128 block, 512 thr, dbuf LDS 64 KiB, 2 blocks/CU,
// 16 waves/CU, glds staging + XOR swizzle byte-identical) with a K-SPLIT wave
// decomposition: 4 spatial waves (2x2, each owning a 64x64 output tile) x 2-way
// K-split (wave's former h-loop role is now fixed: ks = wave>>2 handles k-half
// ks*64 of every BK=128 tile). Raises LDS-read intensity 42.7 -> 64 ops/B:
// per tile a wave reads 4 A-frags + 4 B-frags (8 KB) for 16 MFMAs. Per-CU LDS
// traffic drops 256 KB -> 192 KB per K-tile (model: 3012 -> 2260 cyc at the
// measured ~85 B/cyc effective rate; MFMA floor 1307). Occupancy and register
// plan guarded: acc 64 + af 16 + bf 4 + addr ~= 110 VGPR < 128 cap (r8 lesson).
// cp = (ks*4+quad)^swz is r4's verified read formula with h:=ks -- swizzle
// cancellation and zero-bank-conflict banking carry over unchanged; acc over
// all 32 tiles x both ks halves sums the full K.
// Epilogue: ks=1 waves dump acc into the (dead) LDS buffers; ks=0 waves add
// and do the dequant+store. Two extra barriers, ~64KB LDS each way.

__global__ __launch_bounds__(512, 4) void gemm_bt_i8(
    const int8_t* __restrict__ A,      // [M,K] int8
    const int8_t* __restrict__ B,      // [N,K] int8
    const float*  __restrict__ sx,     // [M] row dequant scale
    const float*  __restrict__ scales, // [N]
    const float*  __restrict__ bias,   // [N]
    float* __restrict__ C)             // [M,N]
{
    __shared__ __align__(16) int8_t As[2 * ATILE];  // 32 KiB
    __shared__ __align__(16) int8_t Bs[2 * BTILE];  // 32 KiB

    const int tid  = threadIdx.x;

    // T1: XCD-aware swizzle. 512 blocks = 8 chunks of 64; chunk = 8(bm) x 8(bn).
    const int bid   = blockIdx.x;
    const int xcd   = bid & 7;
    const int local = bid >> 3;                       // 0..63
    const int bm    = (xcd >> 2) * 8 + (local >> 3);  // 0..15
    const int bn    = (xcd & 3) * 8 + (local & 7);    // 0..31

    const int lane = tid & 63;
    const int wave = tid >> 6;           // 0..7
    const int spat = wave & 3;           // spatial 2x2
    const int ks   = wave >> 2;          // K-split half: 0 or 1
    const int wm   = (spat >> 1) * 64;   // 0 or 64
    const int wn   = (spat & 1) * 64;    // 0 or 64
    const int l16  = lane & 15;
    const int quad = lane >> 4;
    const int swz  = l16 & 7;
    // Fixed physical colgroup base for this wave's k-half (r4 formula, h := ks).
    const int cp   = (ks * 4 + quad) ^ swz;

    // Staging (r4 scheme, byte-identical): 512 thr x 16 B = 8 KiB/instr;
    // 2 instrs per 16 KiB tile. thread t -> row = t>>3 (+64 for seg1), phys
    // colgroup = t&7; global colgroup = phys ^ (row&7). LDS byte addr = 16*t.
    const int srow = tid >> 3;           // 0..63
    const int cgl  = (tid & 7) ^ (srow & 7);

    const int8_t* ga0 = A + (size_t)(bm * BM + srow)      * K_DIM + cgl * 16;
    const int8_t* ga1 = A + (size_t)(bm * BM + 64 + srow) * K_DIM + cgl * 16;
    const int8_t* gb0 = B + (size_t)(bn * BN + srow)      * K_DIM + cgl * 16;
    const int8_t* gb1 = B + (size_t)(bn * BN + 64 + srow) * K_DIM + cgl * 16;
    const int la0 = tid * 16;
    const int la1 = 8192 + tid * 16;

    // Prologue: stage tile 0 into buffer 0.
    load_lds16(ga0, As + la0);
    load_lds16(ga1, As + la1);
    load_lds16(gb0, Bs + la0);
    load_lds16(gb1, Bs + la1);

    int4v acc[4][4] = {};

    int cur = 0;
    for (int k0 = 0; k0 < K_DIM; k0 += BK, cur ^= 1) {
        __syncthreads();   // drains glds for buf[cur]; all waves done with buf[cur^1]

        const int kn = k0 + BK;
        if (kn < K_DIM) {  // prefetch next tile, in flight during compute
            const int nb = (cur ^ 1);
            load_lds16(ga0 + kn, As + nb * ATILE + la0);
            load_lds16(ga1 + kn, As + nb * ATILE + la1);
            load_lds16(gb0 + kn, Bs + nb * BTILE + la0);
            load_lds16(gb1 + kn, Bs + nb * BTILE + la1);
        }

        const int8_t* Ab = As + cur * ATILE;
        const int8_t* Bb = Bs + cur * BTILE;

        int4v af[4];
#pragma unroll
        for (int i = 0; i < 4; i++)
            af[i] = *(const int4v*)(Ab + (wm + i * 16 + l16) * BK + cp * 16);
#pragma unroll
        for (int j = 0; j < 4; j++) {
            int4v bf = *(const int4v*)(Bb + (wn + j * 16 + l16) * BK + cp * 16);
#pragma unroll
            for (int i = 0; i < 4; i++)
                acc[i][j] = __builtin_amdgcn_mfma_i32_16x16x64_i8(
                    af[i], bf, acc[i][j], 0, 0, 0);
        }
    }

    // ---- K-split reduction: ks=1 waves dump acc to LDS, ks=0 waves add ----
    __syncthreads();   // all K-loop LDS reads complete -> buffers reusable

    // 16 KiB per spatial wave: spat 0,1 -> As halves; spat 2,3 -> Bs halves.
    int8_t* rbase = (spat < 2 ? As : Bs) + (spat & 1) * 16384;

    if (ks == 1) {
#pragma unroll
        for (int i = 0; i < 4; i++)
#pragma unroll
            for (int j = 0; j < 4; j++)
                *(int4v*)(rbase + ((i * 4 + j) * 64 + lane) * 16) = acc[i][j];
    }
    __syncthreads();

    if (ks == 0) {
#pragma unroll
        for (int i = 0; i < 4; i++)
#pragma unroll
            for (int j = 0; j < 4; j++)
                acc[i][j] += *(const int4v*)(rbase + ((i * 4 + j) * 64 + lane) * 16);

        // Row dequant scales for this lane's 16 output rows.
        float sxr[16];
#pragma unroll
        for (int i = 0; i < 4; i++)
#pragma unroll
            for (int r = 0; r < 4; r++)
                sxr[i * 4 + r] = sx[bm * BM + wm + i * 16 + quad * 4 + r];

        // C/D layout (shape-determined, verified): col = lane&15, row = quad*4 + reg.
#pragma unroll
        for (int j = 0; j < 4; j++) {
            const int col = bn * BN + wn + j * 16 + l16;
            const float s = scales[col];
            const float b = bias[col];
#pragma unroll
            for (int i = 0; i < 4; i++) {
                const int row0 = bm * BM + wm + i * 16 + quad * 4;
#pragma unroll
                for (int r = 0; r < 4; r++) {
                    C[(size_t)(row0 + r) * N_DIM + col] =
                        (float)acc[i][j][r] * (sxr[i * 4 + r] * s) + b;
                }
            }
        }
    }
}

// ---------- launch ----------

extern "C" void kernel_launch(void* const* d_in, const int* in_sizes, int n_in,
                              void* d_out, int out_size, void* d_ws, size_t ws_size,
                              hipStream_t stream) {
    const float* x      = (const float*)d_in[0];   // [2,1024,4096] fp32
    const int*   w      = (const int*)d_in[1];     // [4096,4096] int, values in [-128,127]
    const float* scales = (const float*)d_in[2];   // [4096]
    const float* bias   = (const float*)d_in[3];   // [4096]
    float*       out    = (float*)d_out;           // [2,1024,4096] fp32

    int8_t* Aq = (int8_t*)d_ws;                                        // 8 MiB
    int8_t* Bq = (int8_t*)d_ws + (size_t)M_DIM * K_DIM;                // 16 MiB
    float*  sx = (float*)((int8_t*)d_ws + (size_t)(M_DIM + N_DIM) * K_DIM); // 8 KiB

    quant_x<<<M_DIM, 256, 0, stream>>>(x, Aq, sx);
    cvt_w8<<<(int)((size_t)N_DIM * K_DIM / 16 / 256), 256, 0, stream>>>(w, Bq);

    // 1-D grid of 512 blocks (16 bm x 32 bn), XCD-swizzled inside the kernel.
    gemm_bt_i8<<<512, 512, 0, stream>>>(Aq, Bq, sx, scales, bias, out);
}